// Round 4
// baseline (527.331 us; speedup 1.0000x reference)
//
#include <hip/hip_runtime.h>
#include <stdint.h>

#define NINPUTS   1024
#define NOUTPUTS  1024
#define NMID      31          // middle layers
#define NN        4096        // neurons per layer
#define W         65536       // bit-array width
#define CHUNK     64          // columns per chunk: one 64-bit ballot packs a row
#define NCHUNKS   (W / CHUNK) // 1024
#define GRID      512         // 2 WGs per CU
#define CPW       (NCHUNKS / GRID)   // 2 chunks per WG
#define THREADS   1024

// Software-pipelined NAND evaluator, CHUNK=64 columns per chunk.
// LDS buffers: P = packed input of NEXT... (current chunk's input at L0),
// X,Y = 4096-row ping-pong state, R = 1024-row result of previous chunk.
// Per layer L of chunk i:
//   top:    issue 2 global row-loads for pack(chunk i+1)   (L>=1)
//   middle: gather-NAND 4096 (or 1024 at L32) neurons from LDS
//   then:   unpack 2 rows of R (chunk i-1 result) -> coalesced global stores
//   bottom: ballot + lane0 LDS write of the rows loaded at top -> P
//   __syncthreads()
// Hazards: P re-filled only after L0 read it (barrier after L0); R rewritten
// at L32 only after unpack finished (spread over L0..L31, barrier after L31).
// Column<->bit mapping: col c0+l <-> bit l of the wave ballot (l = lane 0..63),
// i.e. word (l>>5), bit (l&31). Output dtype: int32 0/1 (verified round 1/2).
__global__ __launch_bounds__(THREADS, 8)
void nand_pipe_kernel(const uint32_t* __restrict__ in,         // [1024][W]
                      const int*      __restrict__ idx_first,  // [NN][2]
                      const uint32_t* __restrict__ mask_first, // [NN]
                      const int*      __restrict__ idx_mid,    // [NMID][NN][2]
                      const uint32_t* __restrict__ mask_mid,   // [NMID][NN]
                      const int*      __restrict__ idx_last,   // [NOUTPUTS][2]
                      const uint32_t* __restrict__ mask_last,  // [NOUTPUTS]
                      uint32_t*       __restrict__ out)        // [NOUTPUTS][W]
{
    __shared__ uint32_t lds[20480];                 // 80 KiB total
    uint32_t* P = lds;                              // 1024 rows x 2 dwords (8 KB)
    uint32_t* X = lds + 2048;                       // 4096 rows x 2 dwords (32 KB)
    uint32_t* Y = lds + 10240;                      // 4096 rows x 2 dwords (32 KB)
    uint32_t* R = lds + 18432;                      // 1024 rows x 2 dwords (8 KB)

    const int t  = threadIdx.x;
    const int l  = t & 63;                          // lane
    const int wv = t >> 6;                          // wave 0..15
    const int wg = blockIdx.x;                      // 0..GRID-1

    for (int i = 0; i < CPW; ++i) {
        const int c0      = (wg + GRID * i) * CHUNK;
        const int c0_next = (wg + GRID * (i + 1)) * CHUNK;   // used only if do_pack
        const int c0_prev = (wg + GRID * (i - 1)) * CHUNK;   // used only if do_unpack
        const bool do_pack   = (i + 1 < CPW);
        const bool do_unpack = (i > 0);

        // ---------------- prologue: pack chunk 0 fully into P ----------------
        if (i == 0) {
            for (int s = 0; s < 32; ++s) {          // wave wv packs rows wv*64..+63
                const int r0 = wv * 64 + 2 * s;
                const uint32_t v0 = in[(size_t)r0 * W + c0 + l];
                const uint32_t v1 = in[(size_t)(r0 + 1) * W + c0 + l];
                const unsigned long long b0 = __ballot(v0 != 0u);
                const unsigned long long b1 = __ballot(v1 != 0u);
                if (l == 0) {
                    uint4 w4;
                    w4.x = (uint32_t)b0;  w4.y = (uint32_t)(b0 >> 32);
                    w4.z = (uint32_t)b1;  w4.w = (uint32_t)(b1 >> 32);
                    *(uint4*)&P[r0 * 2] = w4;
                }
            }
            __syncthreads();
        }

        // ---------------- 33 layers with interleaved pack/unpack ----------------
        for (int L = 0; L <= 32; ++L) {
            // (a) issue next-chunk input loads early (latency hides under LDS work)
            uint32_t pv0 = 0, pv1 = 0;
            int pr0 = 0;
            if (do_pack && L >= 1) {
                pr0 = wv * 64 + 2 * (L - 1);
                pv0 = in[(size_t)pr0 * W + c0_next + l];
                pv1 = in[(size_t)(pr0 + 1) * W + c0_next + l];
            }

            // (b) neuron gather-NAND in LDS
            if (L == 0) {
                #pragma unroll
                for (int k = 0; k < NN / THREADS; ++k) {
                    const int n = k * THREADS + t;
                    const int2 ij = ((const int2*)idx_first)[n];
                    const uint32_t xm = mask_first[n] ? 0xFFFFFFFFu : 0u;
                    const uint2 a = *(const uint2*)&P[ij.x * 2];
                    const uint2 b = *(const uint2*)&P[ij.y * 2];
                    uint2 r;
                    r.x = (a.x & b.x) ^ xm;  r.y = (a.y & b.y) ^ xm;
                    *(uint2*)&X[n * 2] = r;
                }
            } else if (L <= 31) {
                const int* idxL      = idx_mid + (size_t)(L - 1) * NN * 2;
                const uint32_t* mL   = mask_mid + (size_t)(L - 1) * NN;
                const uint32_t* src  = (L & 1) ? X : Y;
                uint32_t*       dst  = (L & 1) ? Y : X;
                #pragma unroll
                for (int k = 0; k < NN / THREADS; ++k) {
                    const int n = k * THREADS + t;
                    const int2 ij = ((const int2*)idxL)[n];
                    const uint32_t xm = mL[n] ? 0xFFFFFFFFu : 0u;
                    const uint2 a = *(const uint2*)&src[ij.x * 2];
                    const uint2 b = *(const uint2*)&src[ij.y * 2];
                    uint2 r;
                    r.x = (a.x & b.x) ^ xm;  r.y = (a.y & b.y) ^ xm;
                    *(uint2*)&dst[n * 2] = r;
                }
            } else {                                 // L == 32: last layer -> R
                const int n = t;                     // 1024 outputs, 1/thread
                const int2 ij = ((const int2*)idx_last)[n];
                const uint32_t xm = mask_last[n] ? 0xFFFFFFFFu : 0u;
                const uint2 a = *(const uint2*)&Y[ij.x * 2];   // L31 (odd) wrote Y
                const uint2 b = *(const uint2*)&Y[ij.y * 2];
                uint2 r;
                r.x = (a.x & b.x) ^ xm;  r.y = (a.y & b.y) ^ xm;
                *(uint2*)&R[n * 2] = r;
            }

            // (c) unpack 2 rows of previous chunk's result -> global
            if (do_unpack && L <= 31) {
                const int r0 = wv * 64 + 2 * L;
                const uint4 w4 = *(const uint4*)&R[r0 * 2];    // broadcast read
                const uint32_t w0 = (l < 32) ? w4.x : w4.y;
                const uint32_t w1 = (l < 32) ? w4.z : w4.w;
                out[(size_t)r0 * W + c0_prev + l]       = (w0 >> (l & 31)) & 1u;
                out[(size_t)(r0 + 1) * W + c0_prev + l] = (w1 >> (l & 31)) & 1u;
            }

            // (d) commit the pack rows issued at (a)
            if (do_pack && L >= 1) {
                const unsigned long long b0 = __ballot(pv0 != 0u);
                const unsigned long long b1 = __ballot(pv1 != 0u);
                if (l == 0) {
                    uint4 w4;
                    w4.x = (uint32_t)b0;  w4.y = (uint32_t)(b0 >> 32);
                    w4.z = (uint32_t)b1;  w4.w = (uint32_t)(b1 >> 32);
                    *(uint4*)&P[pr0 * 2] = w4;
                }
            }
            __syncthreads();
        }
    }

    // ---------------- epilogue: unpack last chunk's result ----------------
    {
        const int c0_last = (wg + GRID * (CPW - 1)) * CHUNK;
        for (int s = 0; s < 32; ++s) {
            const int r0 = wv * 64 + 2 * s;
            const uint4 w4 = *(const uint4*)&R[r0 * 2];
            const uint32_t w0 = (l < 32) ? w4.x : w4.y;
            const uint32_t w1 = (l < 32) ? w4.z : w4.w;
            out[(size_t)r0 * W + c0_last + l]       = (w0 >> (l & 31)) & 1u;
            out[(size_t)(r0 + 1) * W + c0_last + l] = (w1 >> (l & 31)) & 1u;
        }
    }
}

extern "C" void kernel_launch(void* const* d_in, const int* in_sizes, int n_in,
                              void* d_out, int out_size, void* d_ws, size_t ws_size,
                              hipStream_t stream) {
    const uint32_t* in         = (const uint32_t*)d_in[0];  // bool as 4-byte 0/1
    const int*      idx_first  = (const int*)d_in[1];
    const uint32_t* mask_first = (const uint32_t*)d_in[2];
    const int*      idx_mid    = (const int*)d_in[3];
    const uint32_t* mask_mid   = (const uint32_t*)d_in[4];
    const int*      idx_last   = (const int*)d_in[5];
    const uint32_t* mask_last  = (const uint32_t*)d_in[6];
    uint32_t*       out        = (uint32_t*)d_out;

    nand_pipe_kernel<<<GRID, THREADS, 0, stream>>>(
        in, idx_first, mask_first, idx_mid, mask_mid, idx_last, mask_last, out);
}

// Round 5
// 201.526 us; speedup vs baseline: 2.6167x; 2.6167x over previous
//
#include <hip/hip_runtime.h>
#include <stdint.h>

#define NINPUTS   1024
#define NOUTPUTS  1024
#define NMID      31          // middle layers
#define NN        4096        // neurons per layer
#define W         65536       // bit-array width
#define CHUNK     128         // columns per chunk (512-B rows: min clean HBM granule)
#define WPN       4           // u32 words per row (CHUNK/32)
#define NCHUNKS   (W / CHUNK) // 512
#define GRID      256         // 1 WG per CU
#define CPW       (NCHUNKS / GRID)   // 2 chunks per WG, pipelined
#define THREADS   1024

// In-WG software pipeline at CHUNK=128 (512-B global bursts — R4 showed 256-B
// bursts amplify HBM traffic ~3x; R2/R3 showed 512-B bursts are clean).
// LDS (160 KiB exactly): P = packed input (16 KB), X/Y = state ping-pong
// (64 KB each), R = packed result (16 KB).
// Per layer L of chunk i:
//   (a) issue next-chunk pack loads (rows 32(L-1)..32L-1), L>=1
//   (b) gather-NAND: L0: P->X, L1..31: ping-pong (odd: X->Y), L32: Y->R
//   (c) unpack prev chunk result rows 32L..32L+31 -> global (L<=31)
//   (d) ballot-commit the rows loaded at (a) into P
//   barrier
// Hazards: P consumed only at L0 (barrier before L1 writes); R drained by L31,
// rewritten at L32; X fully rewritten at L0 (last read at L31 prev chunk).
// Bit mapping (verified R2/R3): col c0 + 4*b + j <-> word j, bit b (b=lane32).
// Output dtype: int32 0/1 (verified R1/R2).
__global__ __launch_bounds__(THREADS, 4)
void nand_pipe128_kernel(const uint32_t* __restrict__ in,         // [1024][W]
                         const int*      __restrict__ idx_first,  // [NN][2]
                         const uint32_t* __restrict__ mask_first, // [NN]
                         const int*      __restrict__ idx_mid,    // [NMID][NN][2]
                         const uint32_t* __restrict__ mask_mid,   // [NMID][NN]
                         const int*      __restrict__ idx_last,   // [NOUTPUTS][2]
                         const uint32_t* __restrict__ mask_last,  // [NOUTPUTS]
                         uint32_t*       __restrict__ out)        // [NOUTPUTS][W]
{
    __shared__ uint32_t lds[40960];          // 160 KiB exactly
    uint32_t* P = lds;                       // 1024 * 4 dwords (16 KB)
    uint32_t* X = lds + 4096;                // 4096 * 4 dwords (64 KB)
    uint32_t* Y = lds + 20480;               // 4096 * 4 dwords (64 KB)
    uint32_t* R = lds + 36864;               // 1024 * 4 dwords (16 KB)

    const int t      = threadIdx.x;
    const int l      = t & 63;               // lane
    const int wv     = t >> 6;               // wave 0..15
    const int lane32 = l & 31;
    const int half   = l >> 5;               // 0/1: which row of the pair
    const int shift  = half ? 32 : 0;
    const int bcol   = blockIdx.x * (CPW * CHUNK);   // 256 cols per WG

    // ---------------- prologue: pack chunk 0 fully into P ----------------
    #pragma unroll 4
    for (int s = 0; s < 32; ++s) {
        const int r = s * 32 + wv * 2 + half;        // this lane's row
        const uint4 v = *(const uint4*)(in + (size_t)r * W + bcol + lane32 * 4);
        const unsigned long long b0 = __ballot(v.x != 0u);
        const unsigned long long b1 = __ballot(v.y != 0u);
        const unsigned long long b2 = __ballot(v.z != 0u);
        const unsigned long long b3 = __ballot(v.w != 0u);
        if (lane32 == 0) {                           // lanes 0 & 32: own rows
            uint4 w;
            w.x = (uint32_t)(b0 >> shift);
            w.y = (uint32_t)(b1 >> shift);
            w.z = (uint32_t)(b2 >> shift);
            w.w = (uint32_t)(b3 >> shift);
            *(uint4*)&P[r * WPN] = w;
        }
    }
    __syncthreads();

    for (int i = 0; i < CPW; ++i) {
        const int c0  = bcol + i * CHUNK;
        const int c0n = bcol + (i + 1) * CHUNK;      // pack source cols
        const int c0p = bcol + (i - 1) * CHUNK;      // unpack dest cols
        const bool do_pack   = (i + 1 < CPW);
        const bool do_unpack = (i > 0);

        for (int L = 0; L <= 32; ++L) {
            // (a) issue next-chunk input loads (hide HBM under LDS gather)
            uint4 pv = {0, 0, 0, 0};
            int   pr = 0;
            if (do_pack && L >= 1) {
                pr = (L - 1) * 32 + wv * 2 + half;
                pv = *(const uint4*)(in + (size_t)pr * W + c0n + lane32 * 4);
            }

            // (b) neuron gather-NAND in LDS
            if (L == 0) {
                #pragma unroll
                for (int k = 0; k < NN / THREADS; ++k) {
                    const int n = k * THREADS + t;
                    const int2 ij = ((const int2*)idx_first)[n];
                    const uint32_t xm = mask_first[n] ? 0xFFFFFFFFu : 0u;
                    const uint4 a = *(const uint4*)&P[ij.x * WPN];
                    const uint4 b = *(const uint4*)&P[ij.y * WPN];
                    uint4 r;
                    r.x = (a.x & b.x) ^ xm;  r.y = (a.y & b.y) ^ xm;
                    r.z = (a.z & b.z) ^ xm;  r.w = (a.w & b.w) ^ xm;
                    *(uint4*)&X[n * WPN] = r;
                }
            } else if (L <= 31) {
                const int*      idxL = idx_mid + (size_t)(L - 1) * NN * 2;
                const uint32_t* mL   = mask_mid + (size_t)(L - 1) * NN;
                const uint32_t* src  = (L & 1) ? X : Y;
                uint32_t*       dst  = (L & 1) ? Y : X;
                #pragma unroll
                for (int k = 0; k < NN / THREADS; ++k) {
                    const int n = k * THREADS + t;
                    const int2 ij = ((const int2*)idxL)[n];
                    const uint32_t xm = mL[n] ? 0xFFFFFFFFu : 0u;
                    const uint4 a = *(const uint4*)&src[ij.x * WPN];
                    const uint4 b = *(const uint4*)&src[ij.y * WPN];
                    uint4 r;
                    r.x = (a.x & b.x) ^ xm;  r.y = (a.y & b.y) ^ xm;
                    r.z = (a.z & b.z) ^ xm;  r.w = (a.w & b.w) ^ xm;
                    *(uint4*)&dst[n * WPN] = r;
                }
            } else {                                 // L == 32: last layer -> R
                const int n = t;                     // 1024 outputs, 1/thread
                const int2 ij = ((const int2*)idx_last)[n];
                const uint32_t xm = mask_last[n] ? 0xFFFFFFFFu : 0u;
                const uint4 a = *(const uint4*)&Y[ij.x * WPN];  // L31 wrote Y
                const uint4 b = *(const uint4*)&Y[ij.y * WPN];
                uint4 r;
                r.x = (a.x & b.x) ^ xm;  r.y = (a.y & b.y) ^ xm;
                r.z = (a.z & b.z) ^ xm;  r.w = (a.w & b.w) ^ xm;
                *(uint4*)&R[n * WPN] = r;
            }

            // (c) unpack 32 rows of previous chunk's result -> global
            if (do_unpack && L <= 31) {
                const int r = L * 32 + wv * 2 + half;
                const uint4 w4 = *(const uint4*)&R[r * WPN];   // uniform per half
                uint4 v;
                v.x = (w4.x >> lane32) & 1u;
                v.y = (w4.y >> lane32) & 1u;
                v.z = (w4.z >> lane32) & 1u;
                v.w = (w4.w >> lane32) & 1u;
                *(uint4*)(out + (size_t)r * W + c0p + lane32 * 4) = v;
            }

            // (d) ballot-commit the pack rows issued at (a)
            if (do_pack && L >= 1) {
                const unsigned long long b0 = __ballot(pv.x != 0u);
                const unsigned long long b1 = __ballot(pv.y != 0u);
                const unsigned long long b2 = __ballot(pv.z != 0u);
                const unsigned long long b3 = __ballot(pv.w != 0u);
                if (lane32 == 0) {
                    uint4 w;
                    w.x = (uint32_t)(b0 >> shift);
                    w.y = (uint32_t)(b1 >> shift);
                    w.z = (uint32_t)(b2 >> shift);
                    w.w = (uint32_t)(b3 >> shift);
                    *(uint4*)&P[pr * WPN] = w;
                }
            }
            __syncthreads();
        }
    }

    // ---------------- epilogue: unpack last chunk's result ----------------
    {
        const int c0l = bcol + (CPW - 1) * CHUNK;
        #pragma unroll 4
        for (int s = 0; s < 32; ++s) {
            const int r = s * 32 + wv * 2 + half;
            const uint4 w4 = *(const uint4*)&R[r * WPN];
            uint4 v;
            v.x = (w4.x >> lane32) & 1u;
            v.y = (w4.y >> lane32) & 1u;
            v.z = (w4.z >> lane32) & 1u;
            v.w = (w4.w >> lane32) & 1u;
            *(uint4*)(out + (size_t)r * W + c0l + lane32 * 4) = v;
        }
    }
}

extern "C" void kernel_launch(void* const* d_in, const int* in_sizes, int n_in,
                              void* d_out, int out_size, void* d_ws, size_t ws_size,
                              hipStream_t stream) {
    const uint32_t* in         = (const uint32_t*)d_in[0];  // bool as 4-byte 0/1
    const int*      idx_first  = (const int*)d_in[1];
    const uint32_t* mask_first = (const uint32_t*)d_in[2];
    const int*      idx_mid    = (const int*)d_in[3];
    const uint32_t* mask_mid   = (const uint32_t*)d_in[4];
    const int*      idx_last   = (const int*)d_in[5];
    const uint32_t* mask_last  = (const uint32_t*)d_in[6];
    uint32_t*       out        = (uint32_t*)d_out;

    nand_pipe128_kernel<<<GRID, THREADS, 0, stream>>>(
        in, idx_first, mask_first, idx_mid, mask_mid, idx_last, mask_last, out);
}

// Round 6
// 158.524 us; speedup vs baseline: 3.3265x; 1.2713x over previous
//
#include <hip/hip_runtime.h>
#include <stdint.h>

#define NINPUTS   1024
#define NOUTPUTS  1024
#define NMID      31          // middle layers
#define NN        4096        // neurons per layer
#define W         65536       // bit-array width
#define CHUNK     128         // columns per chunk (512-B rows: min clean HBM granule)
#define WPN       4           // u32 words per row (CHUNK/32)
#define NCHUNKS   (W / CHUNK) // 512
#define GRID      256         // 1 WG per CU
#define CPW       (NCHUNKS / GRID)   // 2 chunks per WG, pipelined
#define THREADS   1024
#define NPAIRS    16          // fused layer-pairs (L0,L1)..(L30,L31); L32 single
#define TBL_BYTES ((size_t)NPAIRS * NN * 16)

// ---------------------------------------------------------------------------
// Prep kernel: build fused 2-layer tables. Pair F computes layer L_{2F+1} from
// layer L_{2F}'s INPUT state:
//   r = (((s[a1]&s[b1])^m1) & ((s[a2]&s[b2])^m2)) ^ m3
// Encoding (uint4 e): e.x = a1*16 | m1<<31; e.y = b1*16;
//                     e.z = a2*16 | m2<<31; e.w = b2*16 | m3<<31.
// First-half layer: F==0 -> (idx_first,mask_first); F>=1 -> mid[2F-1].
// Second-half layer: mid[2F].
// ---------------------------------------------------------------------------
__global__ void build_tbl_kernel(const int*      __restrict__ idx_first,
                                 const uint32_t* __restrict__ mask_first,
                                 const int*      __restrict__ idx_mid,
                                 const uint32_t* __restrict__ mask_mid,
                                 uint4*          __restrict__ tbl)
{
    const int tid = blockIdx.x * blockDim.x + threadIdx.x;   // 0..65535
    const int F = tid >> 12;
    const int n = tid & (NN - 1);

    const int*      i1;
    const uint32_t* m1;
    if (F == 0) { i1 = idx_first; m1 = mask_first; }
    else        { i1 = idx_mid + (size_t)(2 * F - 1) * NN * 2;
                  m1 = mask_mid + (size_t)(2 * F - 1) * NN; }
    const int*      i2 = idx_mid + (size_t)(2 * F) * NN * 2;
    const uint32_t* m2 = mask_mid + (size_t)(2 * F) * NN;

    const int j = i2[2 * n];
    const int k = i2[2 * n + 1];
    uint4 e;
    e.x = (uint32_t)(i1[2 * j]     * 16) | (m1[j] ? 0x80000000u : 0u);
    e.y = (uint32_t)(i1[2 * j + 1] * 16);
    e.z = (uint32_t)(i1[2 * k]     * 16) | (m1[k] ? 0x80000000u : 0u);
    e.w = (uint32_t)(i1[2 * k + 1] * 16) | (m2[n] ? 0x80000000u : 0u);
    tbl[(size_t)F * NN + n] = e;
}

// ---------------------------------------------------------------------------
// Main kernel: 17 rounds/chunk (16 fused pairs + last layer), pipelined
// pack/unpack as R5. Table entries for round F+1 prefetched into registers
// during round F, so the gather phase has no vmem dependency.
// LDS 160 KiB: P (16K) | X (64K) | Y (64K) | R (16K).
// Dataflow: P -(F0)-> X -(F1)-> Y -(F2)-> X ... F odd: X->Y, F even: Y->X.
// F15 (odd) writes Y; L32 reads Y -> R.
// ---------------------------------------------------------------------------
__global__ __launch_bounds__(THREADS, 4)
void nand_fused_kernel(const uint32_t* __restrict__ in,         // [1024][W]
                       const uint4*    __restrict__ tbl,        // [16][NN]
                       const int*      __restrict__ idx_last,   // [NOUTPUTS][2]
                       const uint32_t* __restrict__ mask_last,  // [NOUTPUTS]
                       uint32_t*       __restrict__ out)        // [NOUTPUTS][W]
{
    __shared__ uint32_t lds[40960];          // 160 KiB exactly
    uint32_t* P = lds;                       // 1024 * 4 dwords (16 KB)
    uint32_t* X = lds + 4096;                // 4096 * 4 dwords (64 KB)
    uint32_t* Y = lds + 20480;               // 4096 * 4 dwords (64 KB)
    uint32_t* R = lds + 36864;               // 1024 * 4 dwords (16 KB)

    const int t      = threadIdx.x;
    const int l      = t & 63;
    const int wv     = t >> 6;               // wave 0..15
    const int lane32 = l & 31;
    const int half   = l >> 5;
    const int shift  = half ? 32 : 0;
    const int bcol   = blockIdx.x * (CPW * CHUNK);

    // ---------------- prologue: pack chunk 0 fully into P ----------------
    #pragma unroll 4
    for (int s = 0; s < 32; ++s) {
        const int r = s * 32 + wv * 2 + half;
        const uint4 v = *(const uint4*)(in + (size_t)r * W + bcol + lane32 * 4);
        const unsigned long long b0 = __ballot(v.x != 0u);
        const unsigned long long b1 = __ballot(v.y != 0u);
        const unsigned long long b2 = __ballot(v.z != 0u);
        const unsigned long long b3 = __ballot(v.w != 0u);
        if (lane32 == 0) {
            uint4 w;
            w.x = (uint32_t)(b0 >> shift);
            w.y = (uint32_t)(b1 >> shift);
            w.z = (uint32_t)(b2 >> shift);
            w.w = (uint32_t)(b3 >> shift);
            *(uint4*)&P[r * WPN] = w;
        }
    }
    __syncthreads();

    for (int i = 0; i < CPW; ++i) {
        const int c0n = bcol + (i + 1) * CHUNK;      // pack source cols
        const int c0p = bcol + (i - 1) * CHUNK;      // unpack dest cols
        const bool do_pack   = (i + 1 < CPW);
        const bool do_unpack = (i > 0);

        // cold-load round-0 table entries for this chunk
        uint4 tc[4], tn[4];
        #pragma unroll
        for (int k = 0; k < 4; ++k) tc[k] = tbl[k * THREADS + t];

        for (int F = 0; F <= 16; ++F) {
            // (a) issue next-chunk input loads (2 rows/thread -> 64 rows/WG)
            uint4 pv0 = {0,0,0,0}, pv1 = {0,0,0,0};
            int pr0 = 0, pr1 = 0;
            if (do_pack && F >= 1) {
                pr0 = (F - 1) * 64 + wv * 2 + half;
                pr1 = pr0 + 32;
                pv0 = *(const uint4*)(in + (size_t)pr0 * W + c0n + lane32 * 4);
                pv1 = *(const uint4*)(in + (size_t)pr1 * W + c0n + lane32 * 4);
            }
            // (a') prefetch next round's table entries
            if (F <= 14) {
                #pragma unroll
                for (int k = 0; k < 4; ++k)
                    tn[k] = tbl[(size_t)(F + 1) * NN + k * THREADS + t];
            }

            // (b) fused gather-NAND (pure LDS + VALU, tables in registers)
            if (F <= 15) {
                const uint32_t* src = (F == 0) ? P : ((F & 1) ? X : Y);
                uint32_t*       dst = (F & 1) ? Y : X;
                #pragma unroll
                for (int k = 0; k < 4; ++k) {
                    const int n = k * THREADS + t;
                    const uint4 e = tc[k];
                    const uint32_t xm1 = (uint32_t)((int32_t)e.x >> 31);
                    const uint32_t xm2 = (uint32_t)((int32_t)e.z >> 31);
                    const uint32_t xm3 = (uint32_t)((int32_t)e.w >> 31);
                    const uint4 a = *(const uint4*)((const char*)src + (e.x & 0xFFFFu));
                    const uint4 b = *(const uint4*)((const char*)src + e.y);
                    const uint4 c = *(const uint4*)((const char*)src + (e.z & 0xFFFFu));
                    const uint4 d = *(const uint4*)((const char*)src + (e.w & 0xFFFFu));
                    uint4 r;
                    r.x = (((a.x & b.x) ^ xm1) & ((c.x & d.x) ^ xm2)) ^ xm3;
                    r.y = (((a.y & b.y) ^ xm1) & ((c.y & d.y) ^ xm2)) ^ xm3;
                    r.z = (((a.z & b.z) ^ xm1) & ((c.z & d.z) ^ xm2)) ^ xm3;
                    r.w = (((a.w & b.w) ^ xm1) & ((c.w & d.w) ^ xm2)) ^ xm3;
                    *(uint4*)&dst[n * WPN] = r;
                }
            } else {                                 // F == 16: last layer Y -> R
                const int n = t;
                const int2 ij = ((const int2*)idx_last)[n];
                const uint32_t xm = mask_last[n] ? 0xFFFFFFFFu : 0u;
                const uint4 a = *(const uint4*)&Y[ij.x * WPN];
                const uint4 b = *(const uint4*)&Y[ij.y * WPN];
                uint4 r;
                r.x = (a.x & b.x) ^ xm;  r.y = (a.y & b.y) ^ xm;
                r.z = (a.z & b.z) ^ xm;  r.w = (a.w & b.w) ^ xm;
                *(uint4*)&R[n * WPN] = r;
            }

            // (c) unpack 64 rows of previous chunk's result -> global
            if (do_unpack && F <= 15) {
                #pragma unroll
                for (int s = 0; s < 2; ++s) {
                    const int r = F * 64 + s * 32 + wv * 2 + half;
                    const uint4 w4 = *(const uint4*)&R[r * WPN];
                    uint4 v;
                    v.x = (w4.x >> lane32) & 1u;
                    v.y = (w4.y >> lane32) & 1u;
                    v.z = (w4.z >> lane32) & 1u;
                    v.w = (w4.w >> lane32) & 1u;
                    *(uint4*)(out + (size_t)r * W + c0p + lane32 * 4) = v;
                }
            }

            // (d) ballot-commit the pack rows issued at (a)
            if (do_pack && F >= 1) {
                {
                    const unsigned long long b0 = __ballot(pv0.x != 0u);
                    const unsigned long long b1 = __ballot(pv0.y != 0u);
                    const unsigned long long b2 = __ballot(pv0.z != 0u);
                    const unsigned long long b3 = __ballot(pv0.w != 0u);
                    if (lane32 == 0) {
                        uint4 w;
                        w.x = (uint32_t)(b0 >> shift);
                        w.y = (uint32_t)(b1 >> shift);
                        w.z = (uint32_t)(b2 >> shift);
                        w.w = (uint32_t)(b3 >> shift);
                        *(uint4*)&P[pr0 * WPN] = w;
                    }
                }
                {
                    const unsigned long long b0 = __ballot(pv1.x != 0u);
                    const unsigned long long b1 = __ballot(pv1.y != 0u);
                    const unsigned long long b2 = __ballot(pv1.z != 0u);
                    const unsigned long long b3 = __ballot(pv1.w != 0u);
                    if (lane32 == 0) {
                        uint4 w;
                        w.x = (uint32_t)(b0 >> shift);
                        w.y = (uint32_t)(b1 >> shift);
                        w.z = (uint32_t)(b2 >> shift);
                        w.w = (uint32_t)(b3 >> shift);
                        *(uint4*)&P[pr1 * WPN] = w;
                    }
                }
            }

            if (F <= 14) {
                #pragma unroll
                for (int k = 0; k < 4; ++k) tc[k] = tn[k];
            }
            __syncthreads();
        }
    }

    // ---------------- epilogue: unpack last chunk's result ----------------
    {
        const int c0l = bcol + (CPW - 1) * CHUNK;
        #pragma unroll 4
        for (int s = 0; s < 32; ++s) {
            const int r = s * 32 + wv * 2 + half;
            const uint4 w4 = *(const uint4*)&R[r * WPN];
            uint4 v;
            v.x = (w4.x >> lane32) & 1u;
            v.y = (w4.y >> lane32) & 1u;
            v.z = (w4.z >> lane32) & 1u;
            v.w = (w4.w >> lane32) & 1u;
            *(uint4*)(out + (size_t)r * W + c0l + lane32 * 4) = v;
        }
    }
}

// ---------------------------------------------------------------------------
// Fallback (R5 kernel, unfused) if workspace is too small for the tables.
// ---------------------------------------------------------------------------
__global__ __launch_bounds__(THREADS, 4)
void nand_pipe128_kernel(const uint32_t* __restrict__ in,
                         const int*      __restrict__ idx_first,
                         const uint32_t* __restrict__ mask_first,
                         const int*      __restrict__ idx_mid,
                         const uint32_t* __restrict__ mask_mid,
                         const int*      __restrict__ idx_last,
                         const uint32_t* __restrict__ mask_last,
                         uint32_t*       __restrict__ out)
{
    __shared__ uint32_t lds[40960];
    uint32_t* P = lds;
    uint32_t* X = lds + 4096;
    uint32_t* Y = lds + 20480;
    uint32_t* R = lds + 36864;

    const int t      = threadIdx.x;
    const int l      = t & 63;
    const int wv     = t >> 6;
    const int lane32 = l & 31;
    const int half   = l >> 5;
    const int shift  = half ? 32 : 0;
    const int bcol   = blockIdx.x * (CPW * CHUNK);

    #pragma unroll 4
    for (int s = 0; s < 32; ++s) {
        const int r = s * 32 + wv * 2 + half;
        const uint4 v = *(const uint4*)(in + (size_t)r * W + bcol + lane32 * 4);
        const unsigned long long b0 = __ballot(v.x != 0u);
        const unsigned long long b1 = __ballot(v.y != 0u);
        const unsigned long long b2 = __ballot(v.z != 0u);
        const unsigned long long b3 = __ballot(v.w != 0u);
        if (lane32 == 0) {
            uint4 w;
            w.x = (uint32_t)(b0 >> shift);  w.y = (uint32_t)(b1 >> shift);
            w.z = (uint32_t)(b2 >> shift);  w.w = (uint32_t)(b3 >> shift);
            *(uint4*)&P[r * WPN] = w;
        }
    }
    __syncthreads();

    for (int i = 0; i < CPW; ++i) {
        const int c0n = bcol + (i + 1) * CHUNK;
        const int c0p = bcol + (i - 1) * CHUNK;
        const bool do_pack   = (i + 1 < CPW);
        const bool do_unpack = (i > 0);

        for (int L = 0; L <= 32; ++L) {
            uint4 pv = {0, 0, 0, 0};
            int   pr = 0;
            if (do_pack && L >= 1) {
                pr = (L - 1) * 32 + wv * 2 + half;
                pv = *(const uint4*)(in + (size_t)pr * W + c0n + lane32 * 4);
            }
            if (L == 0) {
                #pragma unroll
                for (int k = 0; k < NN / THREADS; ++k) {
                    const int n = k * THREADS + t;
                    const int2 ij = ((const int2*)idx_first)[n];
                    const uint32_t xm = mask_first[n] ? 0xFFFFFFFFu : 0u;
                    const uint4 a = *(const uint4*)&P[ij.x * WPN];
                    const uint4 b = *(const uint4*)&P[ij.y * WPN];
                    uint4 r;
                    r.x = (a.x & b.x) ^ xm;  r.y = (a.y & b.y) ^ xm;
                    r.z = (a.z & b.z) ^ xm;  r.w = (a.w & b.w) ^ xm;
                    *(uint4*)&X[n * WPN] = r;
                }
            } else if (L <= 31) {
                const int*      idxL = idx_mid + (size_t)(L - 1) * NN * 2;
                const uint32_t* mL   = mask_mid + (size_t)(L - 1) * NN;
                const uint32_t* src  = (L & 1) ? X : Y;
                uint32_t*       dst  = (L & 1) ? Y : X;
                #pragma unroll
                for (int k = 0; k < NN / THREADS; ++k) {
                    const int n = k * THREADS + t;
                    const int2 ij = ((const int2*)idxL)[n];
                    const uint32_t xm = mL[n] ? 0xFFFFFFFFu : 0u;
                    const uint4 a = *(const uint4*)&src[ij.x * WPN];
                    const uint4 b = *(const uint4*)&src[ij.y * WPN];
                    uint4 r;
                    r.x = (a.x & b.x) ^ xm;  r.y = (a.y & b.y) ^ xm;
                    r.z = (a.z & b.z) ^ xm;  r.w = (a.w & b.w) ^ xm;
                    *(uint4*)&dst[n * WPN] = r;
                }
            } else {
                const int n = t;
                const int2 ij = ((const int2*)idx_last)[n];
                const uint32_t xm = mask_last[n] ? 0xFFFFFFFFu : 0u;
                const uint4 a = *(const uint4*)&Y[ij.x * WPN];
                const uint4 b = *(const uint4*)&Y[ij.y * WPN];
                uint4 r;
                r.x = (a.x & b.x) ^ xm;  r.y = (a.y & b.y) ^ xm;
                r.z = (a.z & b.z) ^ xm;  r.w = (a.w & b.w) ^ xm;
                *(uint4*)&R[n * WPN] = r;
            }
            if (do_unpack && L <= 31) {
                const int r = L * 32 + wv * 2 + half;
                const uint4 w4 = *(const uint4*)&R[r * WPN];
                uint4 v;
                v.x = (w4.x >> lane32) & 1u;  v.y = (w4.y >> lane32) & 1u;
                v.z = (w4.z >> lane32) & 1u;  v.w = (w4.w >> lane32) & 1u;
                *(uint4*)(out + (size_t)r * W + c0p + lane32 * 4) = v;
            }
            if (do_pack && L >= 1) {
                const unsigned long long b0 = __ballot(pv.x != 0u);
                const unsigned long long b1 = __ballot(pv.y != 0u);
                const unsigned long long b2 = __ballot(pv.z != 0u);
                const unsigned long long b3 = __ballot(pv.w != 0u);
                if (lane32 == 0) {
                    uint4 w;
                    w.x = (uint32_t)(b0 >> shift);  w.y = (uint32_t)(b1 >> shift);
                    w.z = (uint32_t)(b2 >> shift);  w.w = (uint32_t)(b3 >> shift);
                    *(uint4*)&P[pr * WPN] = w;
                }
            }
            __syncthreads();
        }
    }
    {
        const int c0l = bcol + (CPW - 1) * CHUNK;
        #pragma unroll 4
        for (int s = 0; s < 32; ++s) {
            const int r = s * 32 + wv * 2 + half;
            const uint4 w4 = *(const uint4*)&R[r * WPN];
            uint4 v;
            v.x = (w4.x >> lane32) & 1u;  v.y = (w4.y >> lane32) & 1u;
            v.z = (w4.z >> lane32) & 1u;  v.w = (w4.w >> lane32) & 1u;
            *(uint4*)(out + (size_t)r * W + c0l + lane32 * 4) = v;
        }
    }
}

extern "C" void kernel_launch(void* const* d_in, const int* in_sizes, int n_in,
                              void* d_out, int out_size, void* d_ws, size_t ws_size,
                              hipStream_t stream) {
    const uint32_t* in         = (const uint32_t*)d_in[0];
    const int*      idx_first  = (const int*)d_in[1];
    const uint32_t* mask_first = (const uint32_t*)d_in[2];
    const int*      idx_mid    = (const int*)d_in[3];
    const uint32_t* mask_mid   = (const uint32_t*)d_in[4];
    const int*      idx_last   = (const int*)d_in[5];
    const uint32_t* mask_last  = (const uint32_t*)d_in[6];
    uint32_t*       out        = (uint32_t*)d_out;

    if (ws_size >= TBL_BYTES) {
        uint4* tbl = (uint4*)d_ws;
        build_tbl_kernel<<<(NPAIRS * NN) / 256, 256, 0, stream>>>(
            idx_first, mask_first, idx_mid, mask_mid, tbl);
        nand_fused_kernel<<<GRID, THREADS, 0, stream>>>(
            in, tbl, idx_last, mask_last, out);
    } else {
        nand_pipe128_kernel<<<GRID, THREADS, 0, stream>>>(
            in, idx_first, mask_first, idx_mid, mask_mid, idx_last, mask_last, out);
    }
}